// Round 5
// baseline (432.819 us; speedup 1.0000x reference)
//
#include <hip/hip_runtime.h>
#include <hip/hip_bf16.h>
#include <cstdint>

#define B_   8
#define S_   2048
#define DIN  512
#define DH   512

typedef __attribute__((ext_vector_type(8))) short  short8;
typedef __attribute__((ext_vector_type(4))) short  short4_;
typedef __attribute__((ext_vector_type(4))) float  float4_;

#if __has_builtin(__builtin_amdgcn_mfma_f32_16x16x16bf16_1k)
#define HAVE_MFMA16 1
#else
#define HAVE_MFMA16 0
#endif

__device__ inline unsigned short f2bf(float f) {
    union { float f; unsigned u; } v; v.f = f;
    unsigned u = v.u;
    u += 0x7fffu + ((u >> 16) & 1u);   // RNE
    return (unsigned short)(u >> 16);
}

// async global->LDS: per-lane global addr, wave-uniform LDS base (+lane*16 by HW)
__device__ inline void gload_lds16(const void* g, void* l) {
    __builtin_amdgcn_global_load_lds(
        (const __attribute__((address_space(1))) void*)g,
        (__attribute__((address_space(3))) void*)l, 16, 0, 0);
}

// DPP lane-permute within 16-lane rows (VALU, no LDS)
template <int C>
__device__ inline float fdpp(float x) {
    return __int_as_float(__builtin_amdgcn_update_dpp(0, __float_as_int(x), C, 0xF, 0xF, true));
}
// full reduce over 16-lane row via reversal butterfly: ^15, ^7, ^3, ^1
__device__ inline float rmax16(float v) {
    v = fmaxf(v, fdpp<0x140>(v));  // row_mirror      (^15)
    v = fmaxf(v, fdpp<0x141>(v));  // row_half_mirror (^7)
    v = fmaxf(v, fdpp<27>(v));     // quad_perm [3,2,1,0] (^3)
    v = fmaxf(v, fdpp<177>(v));    // quad_perm [1,0,3,2] (^1)
    return v;
}
__device__ inline float rsum16(float v) {
    v += fdpp<0x140>(v);
    v += fdpp<0x141>(v);
    v += fdpp<27>(v);
    v += fdpp<177>(v);
    return v;
}

// ---------------------------------------------------------------------------
// Kernel 0: fp32 -> bf16 conversion of x and Wq/Wk/Wv (scratch in d_out).
// ---------------------------------------------------------------------------
__global__ __launch_bounds__(256) void conv_bf16(
    const float* __restrict__ x,
    const float* __restrict__ Wq, const float* __restrict__ Wk, const float* __restrict__ Wv,
    unsigned short* __restrict__ xb, unsigned short* __restrict__ wb)
{
    const int NX4 = (B_ * S_ * DIN) / 4;
    const int NW4 = (DH * DIN) / 4;
    const int total = NX4 + 3 * NW4;
    for (int i = blockIdx.x * blockDim.x + threadIdx.x; i < total;
         i += gridDim.x * blockDim.x) {
        const float4_* src; unsigned short* dst; int j;
        if (i < NX4)             { src = (const float4_*)x;  dst = xb;            j = i; }
        else if (i < NX4 + NW4)  { src = (const float4_*)Wq; dst = wb;            j = i - NX4; }
        else if (i < NX4 + 2*NW4){ src = (const float4_*)Wk; dst = wb + DH*DIN;   j = i - NX4 - NW4; }
        else                     { src = (const float4_*)Wv; dst = wb + 2*DH*DIN; j = i - NX4 - 2*NW4; }
        float4_ v = src[j];
        short4_ o;
        o[0] = (short)f2bf(v[0]); o[1] = (short)f2bf(v[1]);
        o[2] = (short)f2bf(v[2]); o[3] = (short)f2bf(v[3]);
        ((short4_*)dst)[j] = o;
    }
}

// ---------------------------------------------------------------------------
// Kernel 1: QKV projection GEMM, 128x128 tiles, double-buffered LDS staging
// (single barrier per k-iter). V epilogue transposes through LDS.
// NOTE: no LDS pointer arrays (gfx950 rejects the static addrspacecast init);
// buffer selection is done with offset arithmetic.
// ---------------------------------------------------------------------------
__global__ __launch_bounds__(256) void qkv_gemm(
    const unsigned short* __restrict__ xb,
    const unsigned short* __restrict__ wb,
    const float* __restrict__ bq, const float* __restrict__ bk, const float* __restrict__ bv,
    unsigned short* __restrict__ qws, unsigned short* __restrict__ kws,
    unsigned short* __restrict__ vtws)
{
    __shared__ __align__(16) unsigned short smem[17408];  // 34.8 KB

    const int tm   = blockIdx.x;
    const int tc   = blockIdx.y;
    const int mat  = tc >> 2;
    const int nb   = (tc & 3) * 128;
    const int tid  = threadIdx.x;
    const int w    = tid >> 6;
    const int lane = tid & 63;
    const int l15  = lane & 15;
    const int quad = lane >> 4;
    const int wm   = (w & 1) * 64;
    const int wn   = (w >> 1) * 64;
    const int m0   = tm * 128;

    const unsigned short* wmat = wb + (size_t)mat * DH * DIN;

    float4_ zero = {0.f, 0.f, 0.f, 0.f};
    float4_ acc[4][4];
    #pragma unroll
    for (int i = 0; i < 4; i++)
        #pragma unroll
        for (int j = 0; j < 4; j++) acc[i][j] = zero;

    const int lr = lane >> 2;
    const int lb = (lane & 3) * 16;

    auto stage = [&](int kk, int bufi) {
        unsigned short* Ab = smem + bufi * 8192;
        unsigned short* Bb = smem + 4096 + bufi * 8192;
        #pragma unroll
        for (int c = 0; c < 2; c++) {
            int r = w * 32 + c * 16;
            const unsigned char* gA = (const unsigned char*)(xb + (size_t)(m0 + r) * DIN + kk);
            gload_lds16(gA + (size_t)lr * (DIN * 2) + lb, (void*)(Ab + r * 32));
            const unsigned char* gB = (const unsigned char*)(wmat + (size_t)(nb + r) * DIN + kk);
            gload_lds16(gB + (size_t)lr * (DIN * 2) + lb, (void*)(Bb + r * 32));
        }
    };

    stage(0, 0);
    for (int ki = 0; ki < 16; ki++) {
        __syncthreads();
        if (ki < 15) stage((ki + 1) * 32, (ki + 1) & 1);
        const unsigned short* Ab = smem + (ki & 1) * 8192;
        const unsigned short* Bb = smem + 4096 + (ki & 1) * 8192;
        short8 af[4], bf[4];
        #pragma unroll
        for (int mt = 0; mt < 4; mt++)
            af[mt] = *(const short8*)(Ab + (wm + mt * 16 + l15) * 32 + quad * 8);
        #pragma unroll
        for (int nt = 0; nt < 4; nt++)
            bf[nt] = *(const short8*)(Bb + (wn + nt * 16 + l15) * 32 + quad * 8);
        #pragma unroll
        for (int mt = 0; mt < 4; mt++)
            #pragma unroll
            for (int nt = 0; nt < 4; nt++)
                acc[mt][nt] = __builtin_amdgcn_mfma_f32_16x16x32_bf16(af[mt], bf[nt], acc[mt][nt], 0, 0, 0);
    }

    if (mat < 2) {
        const float* bias  = (mat == 0) ? bq : bk;
        const float  scale = (mat == 0) ? 0.044194173824159216f : 1.0f;  // 1/sqrt(512) on Q
        unsigned short* dst = (mat == 0) ? qws : kws;
        #pragma unroll
        for (int nt = 0; nt < 4; nt++) {
            int n = nb + wn + nt * 16 + l15;
            float bv_ = bias[n];
            #pragma unroll
            for (int mt = 0; mt < 4; mt++) {
                #pragma unroll
                for (int r = 0; r < 4; r++) {
                    int m = m0 + wm + mt * 16 + quad * 4 + r;
                    dst[(size_t)m * DH + n] = f2bf((acc[mt][nt][r] + bv_) * scale);
                }
            }
        }
    } else {
        __syncthreads();   // done reading staging buffers before reuse as trans
        unsigned short* trans = smem;   // [128 dh][136]
        #pragma unroll
        for (int nt = 0; nt < 4; nt++) {
            int dloc = wn + nt * 16 + l15;
            float bv_ = bv[nb + dloc];
            #pragma unroll
            for (int mt = 0; mt < 4; mt++) {
                short4_ pk;
                #pragma unroll
                for (int r = 0; r < 4; r++) pk[r] = (short)f2bf(acc[mt][nt][r] + bv_);
                *(short4_*)(trans + dloc * 136 + wm + mt * 16 + quad * 4) = pk;
            }
        }
        __syncthreads();
        int d  = tid >> 1;
        int ch = tid & 1;
        const short8* src = (const short8*)(trans + d * 136 + ch * 64);
        int bi = m0 >> 11;
        unsigned short* dst = vtws + (((size_t)(bi * DH + nb + d)) << 11) + (m0 & 2047) + ch * 64;
        #pragma unroll
        for (int j = 0; j < 8; j++) ((short8*)dst)[j] = src[j];
    }
}

// ---------------------------------------------------------------------------
// Kernel 2: flash attention, key-split within block.
// 256 blocks x 512 threads (8 waves): group 0 = keys 0..1023, group 1 =
// keys 1024..2047, same 64 q-rows; online-softmax states merged via LDS at
// the end. 2 waves/SIMD. Per group: 16-key K and V tiles, double-buffered,
// staged via global_load_lds. K rows packed 1 KB with XOR-16B-unit swizzle.
// Softmax reductions via DPP (no LDS). PV at true K=16 when available.
// ---------------------------------------------------------------------------
__global__ __launch_bounds__(512, 2) void attn(
    const unsigned short* __restrict__ qws,
    const unsigned short* __restrict__ kws,
    const unsigned short* __restrict__ vtws,
    float* __restrict__ out)
{
#if HAVE_MFMA16
    constexpr int PSTR = 40;            // P row stride bytes (b64-aligned, bank-spread)
#else
    constexpr int PSTR = 80;            // 32-key rows (upper 16 zero), b128-aligned
#endif
    __shared__ __align__(16) unsigned char smem[131072 + 8 * 16 * PSTR];

    unsigned char* kbuf = smem;            // [g][buf][16 KB]
    unsigned char* vbuf = smem + 65536;    // [g][buf][16 KB]
    unsigned char* pbuf = smem + 131072;   // [8 waves][16*PSTR]

    const int bid  = blockIdx.x;
    const int b    = bid & 7;              // batch == XCD slot
    const int qt   = bid >> 3;
    const int tid  = threadIdx.x;
    const int w    = tid >> 6;             // 0..7
    const int g    = w >> 2;               // key-group
    const int wl   = w & 3;                // wave within group
    const int lane = tid & 63;
    const int l15  = lane & 15;
    const int quad = lane >> 4;

    const int grow = b * S_ + qt * 64 + wl * 16;

    const unsigned short* kgrp = kws + (size_t)(b * S_ + g * 1024) * DH;
    const unsigned short* vgrp = vtws + (((size_t)b * DH) << 11) + g * 1024;

    unsigned char* kb = kbuf + g * 32768;
    unsigned char* vb = vbuf + g * 32768;
    unsigned short* pw = (unsigned short*)(pbuf + w * 16 * PSTR);

#if !HAVE_MFMA16
    // zero upper 16 key columns of P once (they stay zero)
    *(uint64_t*)(pbuf + w * 16 * PSTR + (lane >> 2) * PSTR + 32 + (lane & 3) * 8) = 0;
#endif

    // Q fragments resident: 64 VGPRs
    short8 qf[16];
    const short8* qp = (const short8*)(qws + (size_t)(grow + l15) * DH);
    #pragma unroll
    for (int ksi = 0; ksi < 16; ksi++) qf[ksi] = qp[ksi * 4 + quad];

    float4_ zero = {0.f, 0.f, 0.f, 0.f};
    float4_ o[32];
    #pragma unroll
    for (int i = 0; i < 32; i++) o[i] = zero;
    float m_[4], l_[4];
    #pragma unroll
    for (int r = 0; r < 4; r++) { m_[r] = -INFINITY; l_[r] = 0.f; }

    // staging: 4 K-row instrs + 4 V-block instrs per wave per tile
    auto stageK = [&](int n, int bufi) {
        #pragma unroll
        for (int i = 0; i < 4; i++) {
            int row = wl * 4 + i;
            const unsigned char* gp = (const unsigned char*)(kgrp + (size_t)(n * 16 + row) * DH);
            gload_lds16(gp + ((lane ^ (row & 7)) << 4), kb + bufi * 16384 + row * 1024);
        }
    };
    auto stageV = [&](int n, int bufi) {
        #pragma unroll
        for (int i = 0; i < 4; i++) {
            int d0 = (wl * 4 + i) * 32;
            const unsigned char* gp = (const unsigned char*)
                (vgrp + ((size_t)(d0 + (lane >> 1)) << 11) + n * 16 + (lane & 1) * 8);
            gload_lds16(gp, vb + bufi * 16384 + d0 * 32);
        }
    };

    stageK(0, 0); stageV(0, 0);
    int cur = 0;

    for (int it = 0; it < 64; it++) {
        __syncthreads();   // buf[cur] staged; prev iter's reads of buf[cur^1] done
        if (it + 1 < 64) { stageK(it + 1, cur ^ 1); stageV(it + 1, cur ^ 1); }

        // ---- QK: 16 q-rows x 16 keys, two depth-8 MFMA chains ----
        const unsigned char* kt_ = kb + cur * 16384;
        float4_ s0 = zero, s1 = zero;
        #pragma unroll
        for (int ksi = 0; ksi < 16; ksi += 2) {
            short8 k0 = *(const short8*)(kt_ + l15 * 1024 + (((ksi * 4 + quad) ^ (l15 & 7)) << 4));
            short8 k1 = *(const short8*)(kt_ + l15 * 1024 + ((((ksi + 1) * 4 + quad) ^ (l15 & 7)) << 4));
            s0 = __builtin_amdgcn_mfma_f32_16x16x32_bf16(qf[ksi],     k0, s0, 0, 0, 0);
            s1 = __builtin_amdgcn_mfma_f32_16x16x32_bf16(qf[ksi + 1], k1, s1, 0, 0, 0);
        }
        float4_ sc = s0 + s1;

        // ---- online softmax (DPP reductions over the 16 key-lanes) ----
        float alpha[4], p[4];
        #pragma unroll
        for (int r = 0; r < 4; r++) {
            float v = rmax16(sc[r]);
            float mn = fmaxf(m_[r], v);
            alpha[r] = __expf(m_[r] - mn);
            m_[r] = mn;
            p[r] = __expf(sc[r] - mn);
            l_[r] = l_[r] * alpha[r] + rsum16(p[r]);
        }

        // ---- P: C-layout -> A-layout via per-wave LDS ----
        #pragma unroll
        for (int r = 0; r < 4; r++)
            pw[(quad * 4 + r) * (PSTR / 2) + l15] = f2bf(p[r]);

        // ---- rescale O only when a new max appeared ----
        float am = fminf(fminf(alpha[0], alpha[1]), fminf(alpha[2], alpha[3]));
        if (__any(am < 1.0f)) {
            #pragma unroll
            for (int ct = 0; ct < 32; ct++)
                #pragma unroll
                for (int r = 0; r < 4; r++) o[ct][r] *= alpha[r];
        }

        // ---- O += P * V ----
        const unsigned char* vt_ = vb + cur * 16384;
#if HAVE_MFMA16
        short4_ pf = *(const short4_*)((const unsigned char*)pw + l15 * PSTR + quad * 8);
        #pragma unroll
        for (int ct = 0; ct < 32; ct++) {
            short4_ vf = *(const short4_*)(vt_ + (ct * 16 + l15) * 32 + quad * 8);
            o[ct] = __builtin_amdgcn_mfma_f32_16x16x16bf16_1k(pf, vf, o[ct], 0, 0, 0);
        }
#else
        short8 pf = *(const short8*)((const unsigned char*)pw + l15 * PSTR + quad * 16);
        #pragma unroll
        for (int ct = 0; ct < 32; ct++) {
            short8 vf = *(const short8*)(vt_ + (ct * 16 + l15) * 32 + (quad & 1) * 16);
            o[ct] = __builtin_amdgcn_mfma_f32_16x16x32_bf16(pf, vf, o[ct], 0, 0, 0);
        }
#endif
        cur ^= 1;
    }

    // ---- merge the two key-groups' online-softmax states via LDS ----
    __syncthreads();
    float* osh  = (float*)smem;               // 4 x 32 KB partner O
    float* mlsh = (float*)(smem + 131072);    // 64 rows x {m,l}
    if (g == 1) {
        float* od = osh + wl * 8192;
        #pragma unroll
        for (int ct = 0; ct < 32; ct++)
            #pragma unroll
            for (int r = 0; r < 4; r++)
                od[(quad * 4 + r) * 512 + ct * 16 + l15] = o[ct][r];
        if (l15 == 0) {
            #pragma unroll
            for (int r = 0; r < 4; r++) {
                int row = wl * 16 + quad * 4 + r;
                mlsh[row * 2]     = m_[r];
                mlsh[row * 2 + 1] = l_[r];
            }
        }
    }
    __syncthreads();
    if (g == 0) {
        const float* od = osh + wl * 8192;
        float a0[4], a1[4], rl[4];
        #pragma unroll
        for (int r = 0; r < 4; r++) {
            int row = wl * 16 + quad * 4 + r;
            float pm = mlsh[row * 2], pl = mlsh[row * 2 + 1];
            float mn = fmaxf(m_[r], pm);
            a0[r] = __expf(m_[r] - mn);
            a1[r] = __expf(pm - mn);
            rl[r] = 1.f / (l_[r] * a0[r] + pl * a1[r]);
        }
        #pragma unroll
        for (int ct = 0; ct < 32; ct++)
            #pragma unroll
            for (int r = 0; r < 4; r++) {
                float v = (o[ct][r] * a0[r] +
                           od[(quad * 4 + r) * 512 + ct * 16 + l15] * a1[r]) * rl[r];
                out[(size_t)(grow + quad * 4 + r) * DH + ct * 16 + l15] = v;
            }
    }
}

extern "C" void kernel_launch(void* const* d_in, const int* in_sizes, int n_in,
                              void* d_out, int out_size, void* d_ws, size_t ws_size,
                              hipStream_t stream) {
    const float* x  = (const float*)d_in[0];
    const float* Wq = (const float*)d_in[1];
    const float* bq = (const float*)d_in[2];
    const float* Wk = (const float*)d_in[3];
    const float* bk = (const float*)d_in[4];
    const float* Wv = (const float*)d_in[5];
    const float* bv = (const float*)d_in[6];
    float* out = (float*)d_out;

    unsigned short* qws = (unsigned short*)d_ws;                 // [16384][512] bf16 (pre-scaled)
    unsigned short* kws = qws + (size_t)B_ * S_ * DH;            // [16384][512] bf16
    unsigned short* vt  = kws + (size_t)B_ * S_ * DH;            // [8][512][2048] bf16

    unsigned short* xb = (unsigned short*)d_out;                 // bf16 staging in d_out
    unsigned short* wb = xb + (size_t)B_ * S_ * DIN;

    conv_bf16<<<dim3(2048), dim3(256), 0, stream>>>(x, Wq, Wk, Wv, xb, wb);
    qkv_gemm<<<dim3(128, 12), dim3(256), 0, stream>>>(xb, wb, bq, bk, bv, qws, kws, vt);
    attn<<<dim3(256), dim3(512), 0, stream>>>(qws, kws, vt, out);
}

// Round 6
// 428.566 us; speedup vs baseline: 1.0099x; 1.0099x over previous
//
#include <hip/hip_runtime.h>
#include <hip/hip_bf16.h>
#include <cstdint>

#define B_   8
#define S_   2048
#define DIN  512
#define DH   512

typedef __attribute__((ext_vector_type(8))) short  short8;
typedef __attribute__((ext_vector_type(4))) short  short4_;
typedef __attribute__((ext_vector_type(4))) float  float4_;

__device__ inline unsigned short f2bf(float f) {
    union { float f; unsigned u; } v; v.f = f;
    unsigned u = v.u;
    u += 0x7fffu + ((u >> 16) & 1u);   // RNE
    return (unsigned short)(u >> 16);
}

// async global->LDS: per-lane global addr, wave-uniform LDS base (+lane*16 by HW)
__device__ inline void gload_lds16(const void* g, void* l) {
    __builtin_amdgcn_global_load_lds(
        (const __attribute__((address_space(1))) void*)g,
        (__attribute__((address_space(3))) void*)l, 16, 0, 0);
}

// DPP lane-permute within 16-lane rows (VALU, no LDS)
template <int C>
__device__ inline float fdpp(float x) {
    return __int_as_float(__builtin_amdgcn_update_dpp(0, __float_as_int(x), C, 0xF, 0xF, true));
}
__device__ inline float rmax16(float v) {
    v = fmaxf(v, fdpp<0x140>(v));  // row_mirror      (^15)
    v = fmaxf(v, fdpp<0x141>(v));  // row_half_mirror (^7)
    v = fmaxf(v, fdpp<27>(v));     // quad_perm [3,2,1,0] (^3)
    v = fmaxf(v, fdpp<177>(v));    // quad_perm [1,0,3,2] (^1)
    return v;
}
__device__ inline float rsum16(float v) {
    v += fdpp<0x140>(v);
    v += fdpp<0x141>(v);
    v += fdpp<27>(v);
    v += fdpp<177>(v);
    return v;
}

// ---------------------------------------------------------------------------
// Kernel 0: fp32 -> bf16 conversion of x and Wq/Wk/Wv (scratch in d_out).
// ---------------------------------------------------------------------------
__global__ __launch_bounds__(256) void conv_bf16(
    const float* __restrict__ x,
    const float* __restrict__ Wq, const float* __restrict__ Wk, const float* __restrict__ Wv,
    unsigned short* __restrict__ xb, unsigned short* __restrict__ wb)
{
    const int NX4 = (B_ * S_ * DIN) / 4;
    const int NW4 = (DH * DIN) / 4;
    const int total = NX4 + 3 * NW4;
    for (int i = blockIdx.x * blockDim.x + threadIdx.x; i < total;
         i += gridDim.x * blockDim.x) {
        const float4_* src; unsigned short* dst; int j;
        if (i < NX4)             { src = (const float4_*)x;  dst = xb;            j = i; }
        else if (i < NX4 + NW4)  { src = (const float4_*)Wq; dst = wb;            j = i - NX4; }
        else if (i < NX4 + 2*NW4){ src = (const float4_*)Wk; dst = wb + DH*DIN;   j = i - NX4 - NW4; }
        else                     { src = (const float4_*)Wv; dst = wb + 2*DH*DIN; j = i - NX4 - 2*NW4; }
        float4_ v = src[j];
        short4_ o;
        o[0] = (short)f2bf(v[0]); o[1] = (short)f2bf(v[1]);
        o[2] = (short)f2bf(v[2]); o[3] = (short)f2bf(v[3]);
        ((short4_*)dst)[j] = o;
    }
}

// ---------------------------------------------------------------------------
// Kernel 1: QKV projection GEMM (unchanged from R5 — works).
// ---------------------------------------------------------------------------
__global__ __launch_bounds__(256) void qkv_gemm(
    const unsigned short* __restrict__ xb,
    const unsigned short* __restrict__ wb,
    const float* __restrict__ bq, const float* __restrict__ bk, const float* __restrict__ bv,
    unsigned short* __restrict__ qws, unsigned short* __restrict__ kws,
    unsigned short* __restrict__ vtws)
{
    __shared__ __align__(16) unsigned short smem[17408];  // 34.8 KB

    const int tm   = blockIdx.x;
    const int tc   = blockIdx.y;
    const int mat  = tc >> 2;
    const int nb   = (tc & 3) * 128;
    const int tid  = threadIdx.x;
    const int w    = tid >> 6;
    const int lane = tid & 63;
    const int l15  = lane & 15;
    const int quad = lane >> 4;
    const int wm   = (w & 1) * 64;
    const int wn   = (w >> 1) * 64;
    const int m0   = tm * 128;

    const unsigned short* wmat = wb + (size_t)mat * DH * DIN;

    float4_ zero = {0.f, 0.f, 0.f, 0.f};
    float4_ acc[4][4];
    #pragma unroll
    for (int i = 0; i < 4; i++)
        #pragma unroll
        for (int j = 0; j < 4; j++) acc[i][j] = zero;

    const int lr = lane >> 2;
    const int lb = (lane & 3) * 16;

    auto stage = [&](int kk, int bufi) {
        unsigned short* Ab = smem + bufi * 8192;
        unsigned short* Bb = smem + 4096 + bufi * 8192;
        #pragma unroll
        for (int c = 0; c < 2; c++) {
            int r = w * 32 + c * 16;
            const unsigned char* gA = (const unsigned char*)(xb + (size_t)(m0 + r) * DIN + kk);
            gload_lds16(gA + (size_t)lr * (DIN * 2) + lb, (void*)(Ab + r * 32));
            const unsigned char* gB = (const unsigned char*)(wmat + (size_t)(nb + r) * DIN + kk);
            gload_lds16(gB + (size_t)lr * (DIN * 2) + lb, (void*)(Bb + r * 32));
        }
    };

    stage(0, 0);
    for (int ki = 0; ki < 16; ki++) {
        __syncthreads();
        if (ki < 15) stage((ki + 1) * 32, (ki + 1) & 1);
        const unsigned short* Ab = smem + (ki & 1) * 8192;
        const unsigned short* Bb = smem + 4096 + (ki & 1) * 8192;
        short8 af[4], bf[4];
        #pragma unroll
        for (int mt = 0; mt < 4; mt++)
            af[mt] = *(const short8*)(Ab + (wm + mt * 16 + l15) * 32 + quad * 8);
        #pragma unroll
        for (int nt = 0; nt < 4; nt++)
            bf[nt] = *(const short8*)(Bb + (wn + nt * 16 + l15) * 32 + quad * 8);
        #pragma unroll
        for (int mt = 0; mt < 4; mt++)
            #pragma unroll
            for (int nt = 0; nt < 4; nt++)
                acc[mt][nt] = __builtin_amdgcn_mfma_f32_16x16x32_bf16(af[mt], bf[nt], acc[mt][nt], 0, 0, 0);
    }

    if (mat < 2) {
        const float* bias  = (mat == 0) ? bq : bk;
        const float  scale = (mat == 0) ? 0.044194173824159216f : 1.0f;  // 1/sqrt(512) on Q
        unsigned short* dst = (mat == 0) ? qws : kws;
        #pragma unroll
        for (int nt = 0; nt < 4; nt++) {
            int n = nb + wn + nt * 16 + l15;
            float bv_ = bias[n];
            #pragma unroll
            for (int mt = 0; mt < 4; mt++) {
                #pragma unroll
                for (int r = 0; r < 4; r++) {
                    int m = m0 + wm + mt * 16 + quad * 4 + r;
                    dst[(size_t)m * DH + n] = f2bf((acc[mt][nt][r] + bv_) * scale);
                }
            }
        }
    } else {
        __syncthreads();
        unsigned short* trans = smem;   // [128 dh][136]
        #pragma unroll
        for (int nt = 0; nt < 4; nt++) {
            int dloc = wn + nt * 16 + l15;
            float bv_ = bv[nb + dloc];
            #pragma unroll
            for (int mt = 0; mt < 4; mt++) {
                short4_ pk;
                #pragma unroll
                for (int r = 0; r < 4; r++) pk[r] = (short)f2bf(acc[mt][nt][r] + bv_);
                *(short4_*)(trans + dloc * 136 + wm + mt * 16 + quad * 4) = pk;
            }
        }
        __syncthreads();
        int d  = tid >> 1;
        int ch = tid & 1;
        const short8* src = (const short8*)(trans + d * 136 + ch * 64);
        int bi = m0 >> 11;
        unsigned short* dst = vtws + (((size_t)(bi * DH + nb + d)) << 11) + (m0 & 2047) + ch * 64;
        #pragma unroll
        for (int j = 0; j < 8; j++) ((short8*)dst)[j] = src[j];
    }
}

// ---------------------------------------------------------------------------
// Kernel 2: flash attention, key-split + transposed PV (dh-sliced O).
// 256 blocks x 512 threads. Group g = keys g*1024..+1024, 64 iters x 16 keys.
// Wave wl does QK+softmax for q-rows wl*16..+16, writes P (shared, [64][40B])
// and alpha; after P-barrier every wave does PV for ALL 64 q-rows x its
// 128-dh slice (V frags read once per group, not once per wave -> 4x less
// LDS traffic). K: XOR-packed 1 KB rows (conflict-free b128 under the
// 8-lane/cycle cohort model). V: [2 halves][512 dh][16 B] (b64, <=2-way).
// End: dh slices concatenate; key-groups merged via LDS.
// ---------------------------------------------------------------------------
__global__ __launch_bounds__(512, 2) void attn(
    const unsigned short* __restrict__ qws,
    const unsigned short* __restrict__ kws,
    const unsigned short* __restrict__ vtws,
    float* __restrict__ out)
{
    // LDS map: [0,131072) K/V tiles (per group 64 KB: K 2x16 KB, V 2x16 KB);
    // epilogue reuses [0,133120) for O-merge (4 slices x 64 rows x 130 dw).
    // 136192: P (2 groups x 64 x 40 B); 141312: alpha (2 x 64 f32);
    // 141824: m,l (2 x 64 x 2 f32). Total 142848.
    __shared__ __align__(16) unsigned char smem[142848];

    const int bid  = blockIdx.x;
    const int b    = bid & 7;              // batch == XCD slot
    const int qt_b = bid >> 3;             // 0..31
    const int tid  = threadIdx.x;
    const int w    = tid >> 6;             // 0..7
    const int g    = w >> 2;               // key-group
    const int wl   = w & 3;                // wave within group
    const int lane = tid & 63;
    const int l15  = lane & 15;
    const int quad = lane >> 4;

    const int qrow0  = b * S_ + qt_b * 64;       // block's first global q-row
    const int myqrow = qrow0 + wl * 16;          // this wave's QK rows

    const unsigned short* kgrp = kws + (size_t)(b * S_ + g * 1024) * DH;
    const unsigned short* vgrp = vtws + (((size_t)b * DH) << 11) + g * 1024;

    unsigned char*  kb  = smem + g * 65536;            // + buf*16384
    unsigned char*  vb  = smem + g * 65536 + 32768;    // + buf*16384
    unsigned short* pg  = (unsigned short*)(smem + 136192 + g * 2560);  // [64][20]
    float*          ab  = (float*)(smem + 141312 + g * 256);            // [64]
    float*          mlb = (float*)(smem + 141824);                      // [2][64][2]

    // Q fragments resident (A-operand for QK): 64 VGPRs
    short8 qf[16];
    {
        const short8* qp = (const short8*)(qws + (size_t)(myqrow + l15) * DH);
        #pragma unroll
        for (int ksi = 0; ksi < 16; ksi++) qf[ksi] = qp[ksi * 4 + quad];
    }

    float4_ zero = {0.f, 0.f, 0.f, 0.f};
    float4_ o[32];                 // [qt*8 + dht]: O[64 q][dh slice wl*128..+128]
    #pragma unroll
    for (int i = 0; i < 32; i++) o[i] = zero;
    float m_[4], l_[4];
    #pragma unroll
    for (int r = 0; r < 4; r++) { m_[r] = -INFINITY; l_[r] = 0.f; }

    // ---- staging (per group; wave wl does 4 K instrs + 4 V instrs) ----
    auto stageK = [&](int n, int bufi) {
        #pragma unroll
        for (int i = 0; i < 4; i++) {
            int row = wl * 4 + i;                      // 0..15 in tile
            const unsigned char* gp =
                (const unsigned char*)(kgrp + (size_t)(n * 16 + row) * DH);
            gload_lds16(gp + ((lane ^ (row & 7)) << 4),
                        kb + bufi * 16384 + row * 1024);
        }
    };
    auto stageV = [&](int n, int bufi) {
        #pragma unroll
        for (int i = 0; i < 4; i++) {
            int j   = wl * 4 + i;                      // 0..15
            int h   = j >> 3;                          // key-half
            int dh0 = (j & 7) * 64;
            const unsigned char* gp = (const unsigned char*)vgrp
                + ((size_t)(dh0 + lane) << 12) + n * 32 + h * 16;
            gload_lds16(gp, vb + bufi * 16384 + h * 8192 + dh0 * 16);
        }
    };

    stageK(0, 0); stageV(0, 0);
    int cur = 0;

    for (int it = 0; it < 64; it++) {
        __syncthreads();   // (a) buf[cur] staged; prev PV reads + P consumed

        // ---- QK: 16 q x 16 keys over d=512, two depth-8 chains ----
        const unsigned char* kt_ = kb + cur * 16384;
        float4_ s0 = zero, s1 = zero;
        #pragma unroll
        for (int ksi = 0; ksi < 16; ksi += 2) {
            short8 k0 = *(const short8*)(kt_ + l15 * 1024 + ((( ksi      * 4 + quad) ^ (l15 & 7)) << 4));
            short8 k1 = *(const short8*)(kt_ + l15 * 1024 + ((((ksi + 1) * 4 + quad) ^ (l15 & 7)) << 4));
            s0 = __builtin_amdgcn_mfma_f32_16x16x32_bf16(qf[ksi],     k0, s0, 0, 0, 0);
            s1 = __builtin_amdgcn_mfma_f32_16x16x32_bf16(qf[ksi + 1], k1, s1, 0, 0, 0);
        }
        float4_ sc = s0 + s1;

        // ---- online softmax over 16 key-lanes (DPP) + P/alpha publish ----
        float alpha[4];
        #pragma unroll
        for (int r = 0; r < 4; r++) {
            float v  = rmax16(sc[r]);
            float mn = fmaxf(m_[r], v);
            alpha[r] = __expf(m_[r] - mn);
            m_[r] = mn;
            float p = __expf(sc[r] - mn);
            l_[r] = l_[r] * alpha[r] + rsum16(p);
            pg[(wl * 16 + quad * 4 + r) * 20 + l15] = f2bf(p);
        }
        if (l15 == 0) {
            #pragma unroll
            for (int r = 0; r < 4; r++) ab[wl * 16 + quad * 4 + r] = alpha[r];
        }

        __syncthreads();   // (b) P + alpha visible (no loads in flight: free drain)

        if (it < 63) { stageK(it + 1, cur ^ 1); stageV(it + 1, cur ^ 1); }

        // ---- rescale O by per-row alpha (broadcast from LDS) ----
        {
            float av[4][4]; float amin = 1.0f;
            #pragma unroll
            for (int qt = 0; qt < 4; qt++)
                #pragma unroll
                for (int r = 0; r < 4; r++) {
                    av[qt][r] = ab[qt * 16 + quad * 4 + r];
                    amin = fminf(amin, av[qt][r]);
                }
            if (__any(amin < 1.0f)) {
                #pragma unroll
                for (int qt = 0; qt < 4; qt++)
                    #pragma unroll
                    for (int dht = 0; dht < 8; dht++)
                        #pragma unroll
                        for (int r = 0; r < 4; r++)
                            o[qt * 8 + dht][r] *= av[qt][r];
            }
        }

        // ---- PV: all 64 q x my 128-dh slice, K=16 MFMA ----
        {
            const unsigned char* vt_ = vb + cur * 16384;
            short4_ pa[4];
            #pragma unroll
            for (int qt = 0; qt < 4; qt++)
                pa[qt] = *(const short4_*)((const unsigned char*)pg + (qt * 16 + l15) * 40 + quad * 8);
            #pragma unroll
            for (int dht = 0; dht < 8; dht++) {
                short4_ vf = *(const short4_*)(vt_ + (quad >> 1) * 8192
                              + (wl * 128 + dht * 16 + l15) * 16 + (quad & 1) * 8);
                #pragma unroll
                for (int qt = 0; qt < 4; qt++)
                    o[qt * 8 + dht] = __builtin_amdgcn_mfma_f32_16x16x16bf16_1k(pa[qt], vf, o[qt * 8 + dht], 0, 0, 0);
            }
        }
        cur ^= 1;
    }

    // ---- epilogue: publish m,l; merge key-groups; store ----
    if (l15 == 0) {
        #pragma unroll
        for (int r = 0; r < 4; r++) {
            int row = wl * 16 + quad * 4 + r;
            mlb[(g * 64 + row) * 2]     = m_[r];
            mlb[(g * 64 + row) * 2 + 1] = l_[r];
        }
    }
    __syncthreads();
    if (g == 1) {
        float* om = (float*)(smem + wl * 33280);   // [64 rows][130 dw]
        #pragma unroll
        for (int qt = 0; qt < 4; qt++)
            #pragma unroll
            for (int dht = 0; dht < 8; dht++)
                #pragma unroll
                for (int r = 0; r < 4; r++)
                    om[(qt * 16 + quad * 4 + r) * 130 + dht * 16 + l15] = o[qt * 8 + dht][r];
    }
    __syncthreads();
    if (g == 0) {
        const float* om = (const float*)(smem + wl * 33280);
        #pragma unroll
        for (int qt = 0; qt < 4; qt++) {
            float a0[4], a1[4], rl[4];
            #pragma unroll
            for (int r = 0; r < 4; r++) {
                int row = qt * 16 + quad * 4 + r;
                float m0 = mlb[row * 2],        l0 = mlb[row * 2 + 1];
                float m1 = mlb[(64 + row) * 2], l1 = mlb[(64 + row) * 2 + 1];
                float mn = fmaxf(m0, m1);
                a0[r] = __expf(m0 - mn);
                a1[r] = __expf(m1 - mn);
                rl[r] = 1.f / (l0 * a0[r] + l1 * a1[r]);
            }
            #pragma unroll
            for (int dht = 0; dht < 8; dht++)
                #pragma unroll
                for (int r = 0; r < 4; r++) {
                    int row = qt * 16 + quad * 4 + r;
                    out[(size_t)(qrow0 + row) * DH + wl * 128 + dht * 16 + l15] =
                        (o[qt * 8 + dht][r] * a0[r] +
                         om[row * 130 + dht * 16 + l15] * a1[r]) * rl[r];
                }
        }
    }
}

extern "C" void kernel_launch(void* const* d_in, const int* in_sizes, int n_in,
                              void* d_out, int out_size, void* d_ws, size_t ws_size,
                              hipStream_t stream) {
    const float* x  = (const float*)d_in[0];
    const float* Wq = (const float*)d_in[1];
    const float* bq = (const float*)d_in[2];
    const float* Wk = (const float*)d_in[3];
    const float* bk = (const float*)d_in[4];
    const float* Wv = (const float*)d_in[5];
    const float* bv = (const float*)d_in[6];
    float* out = (float*)d_out;

    unsigned short* qws = (unsigned short*)d_ws;                 // [16384][512] bf16 (pre-scaled)
    unsigned short* kws = qws + (size_t)B_ * S_ * DH;            // [16384][512] bf16
    unsigned short* vt  = kws + (size_t)B_ * S_ * DH;            // [8][512][2048] bf16

    unsigned short* xb = (unsigned short*)d_out;                 // bf16 staging in d_out
    unsigned short* wb = xb + (size_t)B_ * S_ * DIN;

    conv_bf16<<<dim3(2048), dim3(256), 0, stream>>>(x, Wq, Wk, Wv, xb, wb);
    qkv_gemm<<<dim3(128, 12), dim3(256), 0, stream>>>(xb, wb, bq, bk, bv, qws, kws, vt);
    attn<<<dim3(256), dim3(512), 0, stream>>>(qws, kws, vt, out);
}

// Round 7
// 333.740 us; speedup vs baseline: 1.2969x; 1.2841x over previous
//
#include <hip/hip_runtime.h>
#include <hip/hip_bf16.h>
#include <cstdint>

#define B_   8
#define S_   2048
#define DIN  512
#define DH   512

typedef __attribute__((ext_vector_type(8))) short  short8;
typedef __attribute__((ext_vector_type(4))) short  short4_;
typedef __attribute__((ext_vector_type(4))) float  float4_;

__device__ inline unsigned short f2bf(float f) {
    union { float f; unsigned u; } v; v.f = f;
    unsigned u = v.u;
    u += 0x7fffu + ((u >> 16) & 1u);   // RNE
    return (unsigned short)(u >> 16);
}

// async global->LDS: per-lane global addr, wave-uniform LDS base (+lane*16 by HW)
__device__ inline void gload_lds16(const void* g, void* l) {
    __builtin_amdgcn_global_load_lds(
        (const __attribute__((address_space(1))) void*)g,
        (__attribute__((address_space(3))) void*)l, 16, 0, 0);
}

// Barrier that drains ONLY the LDS counter (lgkmcnt) — leaves in-flight
// global_load_lds (vmcnt) running. Used between P-write and P-read so the
// K/V staging issued at the top of the iteration is not drained mid-iter.
__device__ inline void barrier_lds_only() {
    __asm__ volatile("s_waitcnt lgkmcnt(0)\n\ts_barrier" ::: "memory");
}

// DPP lane-permute within 16-lane rows (VALU, no LDS)
template <int C>
__device__ inline float fdpp(float x) {
    return __int_as_float(__builtin_amdgcn_update_dpp(0, __float_as_int(x), C, 0xF, 0xF, true));
}
__device__ inline float rmax16(float v) {
    v = fmaxf(v, fdpp<0x140>(v));  // row_mirror      (^15)
    v = fmaxf(v, fdpp<0x141>(v));  // row_half_mirror (^7)
    v = fmaxf(v, fdpp<27>(v));     // quad_perm [3,2,1,0] (^3)
    v = fmaxf(v, fdpp<177>(v));    // quad_perm [1,0,3,2] (^1)
    return v;
}
__device__ inline float rsum16(float v) {
    v += fdpp<0x140>(v);
    v += fdpp<0x141>(v);
    v += fdpp<27>(v);
    v += fdpp<177>(v);
    return v;
}

// ---------------------------------------------------------------------------
// Kernel 0: fp32 -> bf16 conversion of x and Wq/Wk/Wv (scratch in d_out).
// ---------------------------------------------------------------------------
__global__ __launch_bounds__(256) void conv_bf16(
    const float* __restrict__ x,
    const float* __restrict__ Wq, const float* __restrict__ Wk, const float* __restrict__ Wv,
    unsigned short* __restrict__ xb, unsigned short* __restrict__ wb)
{
    const int NX4 = (B_ * S_ * DIN) / 4;
    const int NW4 = (DH * DIN) / 4;
    const int total = NX4 + 3 * NW4;
    for (int i = blockIdx.x * blockDim.x + threadIdx.x; i < total;
         i += gridDim.x * blockDim.x) {
        const float4_* src; unsigned short* dst; int j;
        if (i < NX4)             { src = (const float4_*)x;  dst = xb;            j = i; }
        else if (i < NX4 + NW4)  { src = (const float4_*)Wq; dst = wb;            j = i - NX4; }
        else if (i < NX4 + 2*NW4){ src = (const float4_*)Wk; dst = wb + DH*DIN;   j = i - NX4 - NW4; }
        else                     { src = (const float4_*)Wv; dst = wb + 2*DH*DIN; j = i - NX4 - 2*NW4; }
        float4_ v = src[j];
        short4_ o;
        o[0] = (short)f2bf(v[0]); o[1] = (short)f2bf(v[1]);
        o[2] = (short)f2bf(v[2]); o[3] = (short)f2bf(v[3]);
        ((short4_*)dst)[j] = o;
    }
}

// ---------------------------------------------------------------------------
// Kernel 1: QKV projection GEMM. V epilogue now writes the TILE-PACKED image:
// vt2[b][tile n of 16 keys][dh 0..511][32B row], with the 8B-chunk XOR
// swizzle pos = q ^ ((dh>>2)&3) baked in. attn stages each 16 KB tile with
// linear coalesced copies and reads conflict-free b64 fragments.
// ---------------------------------------------------------------------------
__global__ __launch_bounds__(256) void qkv_gemm(
    const unsigned short* __restrict__ xb,
    const unsigned short* __restrict__ wb,
    const float* __restrict__ bq, const float* __restrict__ bk, const float* __restrict__ bv,
    unsigned short* __restrict__ qws, unsigned short* __restrict__ kws,
    unsigned short* __restrict__ vt2)
{
    __shared__ __align__(16) unsigned short smem[17408];  // 34.8 KB

    const int tm   = blockIdx.x;
    const int tc   = blockIdx.y;
    const int mat  = tc >> 2;
    const int nb   = (tc & 3) * 128;
    const int tid  = threadIdx.x;
    const int w    = tid >> 6;
    const int lane = tid & 63;
    const int l15  = lane & 15;
    const int quad = lane >> 4;
    const int wm   = (w & 1) * 64;
    const int wn   = (w >> 1) * 64;
    const int m0   = tm * 128;

    const unsigned short* wmat = wb + (size_t)mat * DH * DIN;

    float4_ zero = {0.f, 0.f, 0.f, 0.f};
    float4_ acc[4][4];
    #pragma unroll
    for (int i = 0; i < 4; i++)
        #pragma unroll
        for (int j = 0; j < 4; j++) acc[i][j] = zero;

    const int lr = lane >> 2;
    const int lb = (lane & 3) * 16;

    auto stage = [&](int kk, int bufi) {
        unsigned short* Ab = smem + bufi * 8192;
        unsigned short* Bb = smem + 4096 + bufi * 8192;
        #pragma unroll
        for (int c = 0; c < 2; c++) {
            int r = w * 32 + c * 16;
            const unsigned char* gA = (const unsigned char*)(xb + (size_t)(m0 + r) * DIN + kk);
            gload_lds16(gA + (size_t)lr * (DIN * 2) + lb, (void*)(Ab + r * 32));
            const unsigned char* gB = (const unsigned char*)(wmat + (size_t)(nb + r) * DIN + kk);
            gload_lds16(gB + (size_t)lr * (DIN * 2) + lb, (void*)(Bb + r * 32));
        }
    };

    stage(0, 0);
    for (int ki = 0; ki < 16; ki++) {
        __syncthreads();
        if (ki < 15) stage((ki + 1) * 32, (ki + 1) & 1);
        const unsigned short* Ab = smem + (ki & 1) * 8192;
        const unsigned short* Bb = smem + 4096 + (ki & 1) * 8192;
        short8 af[4], bf[4];
        #pragma unroll
        for (int mt = 0; mt < 4; mt++)
            af[mt] = *(const short8*)(Ab + (wm + mt * 16 + l15) * 32 + quad * 8);
        #pragma unroll
        for (int nt = 0; nt < 4; nt++)
            bf[nt] = *(const short8*)(Bb + (wn + nt * 16 + l15) * 32 + quad * 8);
        #pragma unroll
        for (int mt = 0; mt < 4; mt++)
            #pragma unroll
            for (int nt = 0; nt < 4; nt++)
                acc[mt][nt] = __builtin_amdgcn_mfma_f32_16x16x32_bf16(af[mt], bf[nt], acc[mt][nt], 0, 0, 0);
    }

    if (mat < 2) {
        const float* bias  = (mat == 0) ? bq : bk;
        const float  scale = (mat == 0) ? 0.044194173824159216f : 1.0f;  // 1/sqrt(512) on Q
        unsigned short* dst = (mat == 0) ? qws : kws;
        #pragma unroll
        for (int nt = 0; nt < 4; nt++) {
            int n = nb + wn + nt * 16 + l15;
            float bv_ = bias[n];
            #pragma unroll
            for (int mt = 0; mt < 4; mt++) {
                #pragma unroll
                for (int r = 0; r < 4; r++) {
                    int m = m0 + wm + mt * 16 + quad * 4 + r;
                    dst[(size_t)m * DH + n] = f2bf((acc[mt][nt][r] + bv_) * scale);
                }
            }
        }
    } else {
        __syncthreads();
        // build [128 dh_local][128 keys] transpose in LDS (stride 136 shorts)
        unsigned short* trans = smem;
        #pragma unroll
        for (int nt = 0; nt < 4; nt++) {
            int dloc = wn + nt * 16 + l15;
            float bv_ = bv[nb + dloc];
            #pragma unroll
            for (int mt = 0; mt < 4; mt++) {
                short4_ pk;
                #pragma unroll
                for (int r = 0; r < 4; r++) pk[r] = (short)f2bf(acc[mt][nt][r] + bv_);
                *(short4_*)(trans + dloc * 136 + wm + mt * 16 + quad * 4) = pk;
            }
        }
        __syncthreads();
        // store tile-packed swizzled image
        int dl   = tid >> 1;           // dh_local 0..127
        int h    = tid & 1;            // key-half
        int dh_g = nb + dl;
        int s4   = (dh_g >> 2) & 3;
        int bi   = m0 >> 11;
        int tile0 = (m0 & 2047) >> 4;  // first tile index within batch
        unsigned char* vt2b = (unsigned char*)vt2;
        #pragma unroll
        for (int t = 0; t < 4; t++) {
            int tl = h * 4 + t;        // tile_local 0..7
            const uint2* c = (const uint2*)(trans + dl * 136 + tl * 16);
            uint2 d0 = c[0 ^ s4], d1 = c[1 ^ s4], d2 = c[2 ^ s4], d3 = c[3 ^ s4];
            unsigned char* dst = vt2b + ((size_t)(bi * 128 + tile0 + tl) << 14) + dh_g * 32;
            ((uint2*)dst)[0] = d0; ((uint2*)dst)[1] = d1;
            ((uint2*)dst)[2] = d2; ((uint2*)dst)[3] = d3;
        }
    }
}

// ---------------------------------------------------------------------------
// Kernel 2: flash attention, key-split + transposed PV (dh-sliced O).
// 256 blocks x 512 threads. Group g = keys g*1024..+1024, 64 iters x 16 keys.
// Staging issued at the TOP of each iteration (full iter of latency hiding);
// the mid-iteration P barrier drains lgkmcnt only, so staging stays in
// flight until the next top __syncthreads. V staged with linear coalesced
// copies from the tile-packed image (no 4KB-stride scatter).
// ---------------------------------------------------------------------------
__global__ __launch_bounds__(512, 2) void attn(
    const unsigned short* __restrict__ qws,
    const unsigned short* __restrict__ kws,
    const unsigned short* __restrict__ vt2,
    float* __restrict__ out)
{
    // LDS map: [0,131072) K/V tiles (per group 64 KB: K 2x16 KB, V 2x16 KB);
    // epilogue reuses [0,133120) for O-merge. 136192: P (2 x 64 x 40 B);
    // 141312: alpha (2 x 64 f32); 141824: m,l (2 x 64 x 2 f32).
    __shared__ __align__(16) unsigned char smem[142848];

    const int bid  = blockIdx.x;
    const int b    = bid & 7;              // batch == XCD slot
    const int qt_b = bid >> 3;             // 0..31
    const int tid  = threadIdx.x;
    const int w    = tid >> 6;             // 0..7
    const int g    = w >> 2;               // key-group
    const int wl   = w & 3;                // wave within group
    const int lane = tid & 63;
    const int l15  = lane & 15;
    const int quad = lane >> 4;

    const int qrow0  = b * S_ + qt_b * 64;
    const int myqrow = qrow0 + wl * 16;

    const unsigned short* kgrp = kws + (size_t)(b * S_ + g * 1024) * DH;
    const unsigned char*  vtb  = (const unsigned char*)vt2;

    unsigned char*  kb  = smem + g * 65536;            // + buf*16384
    unsigned char*  vb  = smem + g * 65536 + 32768;    // + buf*16384
    unsigned short* pg  = (unsigned short*)(smem + 136192 + g * 2560);  // [64][20]
    float*          ab  = (float*)(smem + 141312 + g * 256);            // [64]
    float*          mlb = (float*)(smem + 141824);                      // [2][64][2]

    // Q fragments resident (A-operand for QK): 64 VGPRs
    short8 qf[16];
    {
        const short8* qp = (const short8*)(qws + (size_t)(myqrow + l15) * DH);
        #pragma unroll
        for (int ksi = 0; ksi < 16; ksi++) qf[ksi] = qp[ksi * 4 + quad];
    }

    float4_ zero = {0.f, 0.f, 0.f, 0.f};
    float4_ o[32];                 // [qt*8 + dht]: O[64 q][dh slice wl*128..+128]
    #pragma unroll
    for (int i = 0; i < 32; i++) o[i] = zero;
    float m_[4], l_[4];
    #pragma unroll
    for (int r = 0; r < 4; r++) { m_[r] = -INFINITY; l_[r] = 0.f; }

    // ---- staging (per group; wave wl does 4 K instrs + 4 V instrs) ----
    auto stageK = [&](int n, int bufi) {
        #pragma unroll
        for (int i = 0; i < 4; i++) {
            int row = wl * 4 + i;
            const unsigned char* gp =
                (const unsigned char*)(kgrp + (size_t)(n * 16 + row) * DH);
            gload_lds16(gp + ((lane ^ (row & 7)) << 4),
                        kb + bufi * 16384 + row * 1024);
        }
    };
    auto stageV = [&](int n, int bufi) {
        const unsigned char* base =
            vtb + ((size_t)(b * 128 + g * 64 + n) << 14) + wl * 4096;
        #pragma unroll
        for (int i = 0; i < 4; i++)
            gload_lds16(base + i * 1024 + lane * 16,
                        vb + bufi * 16384 + wl * 4096 + i * 1024);
    };

    stageK(0, 0); stageV(0, 0);
    int cur = 0;

    for (int it = 0; it < 64; it++) {
        __syncthreads();   // buf[cur] staged (vmcnt drained after a FULL iter)

        if (it < 63) { stageK(it + 1, cur ^ 1); stageV(it + 1, cur ^ 1); }

        // ---- QK: 16 q x 16 keys over d=512, two depth-8 chains ----
        const unsigned char* kt_ = kb + cur * 16384;
        float4_ s0 = zero, s1 = zero;
        #pragma unroll
        for (int ksi = 0; ksi < 16; ksi += 2) {
            short8 k0 = *(const short8*)(kt_ + l15 * 1024 + ((( ksi      * 4 + quad) ^ (l15 & 7)) << 4));
            short8 k1 = *(const short8*)(kt_ + l15 * 1024 + ((((ksi + 1) * 4 + quad) ^ (l15 & 7)) << 4));
            s0 = __builtin_amdgcn_mfma_f32_16x16x32_bf16(qf[ksi],     k0, s0, 0, 0, 0);
            s1 = __builtin_amdgcn_mfma_f32_16x16x32_bf16(qf[ksi + 1], k1, s1, 0, 0, 0);
        }
        float4_ sc = s0 + s1;

        // ---- online softmax over 16 key-lanes (DPP) + P/alpha publish ----
        float alpha[4];
        #pragma unroll
        for (int r = 0; r < 4; r++) {
            float v  = rmax16(sc[r]);
            float mn = fmaxf(m_[r], v);
            alpha[r] = __expf(m_[r] - mn);
            m_[r] = mn;
            float p = __expf(sc[r] - mn);
            l_[r] = l_[r] * alpha[r] + rsum16(p);
            pg[(wl * 16 + quad * 4 + r) * 20 + l15] = f2bf(p);
        }
        if (l15 == 0) {
            #pragma unroll
            for (int r = 0; r < 4; r++) ab[wl * 16 + quad * 4 + r] = alpha[r];
        }

        barrier_lds_only();   // P + alpha visible; staging stays in flight

        // ---- rescale O by per-row alpha (broadcast from LDS) ----
        {
            float av[4][4]; float amin = 1.0f;
            #pragma unroll
            for (int qt = 0; qt < 4; qt++)
                #pragma unroll
                for (int r = 0; r < 4; r++) {
                    av[qt][r] = ab[qt * 16 + quad * 4 + r];
                    amin = fminf(amin, av[qt][r]);
                }
            if (__any(amin < 1.0f)) {
                #pragma unroll
                for (int qt = 0; qt < 4; qt++)
                    #pragma unroll
                    for (int dht = 0; dht < 8; dht++)
                        #pragma unroll
                        for (int r = 0; r < 4; r++)
                            o[qt * 8 + dht][r] *= av[qt][r];
            }
        }

        // ---- PV: all 64 q x my 128-dh slice, K=16 MFMA ----
        {
            const unsigned char* vt_ = vb + cur * 16384;
            short4_ pa[4];
            #pragma unroll
            for (int qt = 0; qt < 4; qt++)
                pa[qt] = *(const short4_*)((const unsigned char*)pg + (qt * 16 + l15) * 40 + quad * 8);
            #pragma unroll
            for (int dht = 0; dht < 8; dht++) {
                int dh_sl = wl * 128 + dht * 16 + l15;
                short4_ vf = *(const short4_*)(vt_ + dh_sl * 32 + ((quad ^ ((dh_sl >> 2) & 3)) << 3));
                #pragma unroll
                for (int qt = 0; qt < 4; qt++)
                    o[qt * 8 + dht] = __builtin_amdgcn_mfma_f32_16x16x16bf16_1k(pa[qt], vf, o[qt * 8 + dht], 0, 0, 0);
            }
        }
        cur ^= 1;
    }

    // ---- epilogue: publish m,l; merge key-groups; store ----
    if (l15 == 0) {
        #pragma unroll
        for (int r = 0; r < 4; r++) {
            int row = wl * 16 + quad * 4 + r;
            mlb[(g * 64 + row) * 2]     = m_[r];
            mlb[(g * 64 + row) * 2 + 1] = l_[r];
        }
    }
    __syncthreads();
    if (g == 1) {
        float* om = (float*)(smem + wl * 33280);   // [64 rows][130 dw]
        #pragma unroll
        for (int qt = 0; qt < 4; qt++)
            #pragma unroll
            for (int dht = 0; dht < 8; dht++)
                #pragma unroll
                for (int r = 0; r < 4; r++)
                    om[(qt * 16 + quad * 4 + r) * 130 + dht * 16 + l15] = o[qt * 8 + dht][r];
    }
    __syncthreads();
    if (g == 0) {
        const float* om = (const float*)(smem + wl * 33280);
        #pragma unroll
        for (int qt = 0; qt < 4; qt++) {
            float a0[4], a1[4], rl[4];
            #pragma unroll
            for (int r = 0; r < 4; r++) {
                int row = qt * 16 + quad * 4 + r;
                float m0 = mlb[row * 2],        l0 = mlb[row * 2 + 1];
                float m1 = mlb[(64 + row) * 2], l1 = mlb[(64 + row) * 2 + 1];
                float mn = fmaxf(m0, m1);
                a0[r] = __expf(m0 - mn);
                a1[r] = __expf(m1 - mn);
                rl[r] = 1.f / (l0 * a0[r] + l1 * a1[r]);
            }
            #pragma unroll
            for (int dht = 0; dht < 8; dht++)
                #pragma unroll
                for (int r = 0; r < 4; r++) {
                    int row = qt * 16 + quad * 4 + r;
                    out[(size_t)(qrow0 + row) * DH + wl * 128 + dht * 16 + l15] =
                        (o[qt * 8 + dht][r] * a0[r] +
                         om[row * 130 + dht * 16 + l15] * a1[r]) * rl[r];
                }
        }
    }
}

extern "C" void kernel_launch(void* const* d_in, const int* in_sizes, int n_in,
                              void* d_out, int out_size, void* d_ws, size_t ws_size,
                              hipStream_t stream) {
    const float* x  = (const float*)d_in[0];
    const float* Wq = (const float*)d_in[1];
    const float* bq = (const float*)d_in[2];
    const float* Wk = (const float*)d_in[3];
    const float* bk = (const float*)d_in[4];
    const float* Wv = (const float*)d_in[5];
    const float* bv = (const float*)d_in[6];
    float* out = (float*)d_out;

    unsigned short* qws = (unsigned short*)d_ws;                 // [16384][512] bf16 (pre-scaled)
    unsigned short* kws = qws + (size_t)B_ * S_ * DH;            // [16384][512] bf16
    unsigned short* vt2 = kws + (size_t)B_ * S_ * DH;            // [8][128 tiles][16KB] bf16

    unsigned short* xb = (unsigned short*)d_out;                 // bf16 staging in d_out
    unsigned short* wb = xb + (size_t)B_ * S_ * DIN;

    conv_bf16<<<dim3(2048), dim3(256), 0, stream>>>(x, Wq, Wk, Wv, xb, wb);
    qkv_gemm<<<dim3(128, 12), dim3(256), 0, stream>>>(xb, wb, bq, bk, bv, qws, kws, vt2);
    attn<<<dim3(256), dim3(512), 0, stream>>>(qws, kws, vt2, out);
}